// Round 3
// baseline (105.682 us; speedup 1.0000x reference)
//
#include <hip/hip_runtime.h>

#define N 1024
#define M 2048
#define P 20
#define THREADS 512   // 8 waves per block, one block per pred row
#define WAVES (THREADS / 64)
#define M_PER_WAVE (M / WAVES)   // 256 gt rows per wave
#define K_ITERS (M_PER_WAVE / 64) // 4

// out layout (float*): matched_points [0,40960) row n at n*40
//                      confidence     [40960,41984) at 40960+n
//                      indices(float) [41984,43008) at 41984+n

__global__ __launch_bounds__(THREADS) void pm_kernel(
    const float* __restrict__ pred, const float* __restrict__ gt,
    float* __restrict__ out)
{
    const int tid  = threadIdx.x;
    const int wave = tid >> 6;
    const int lane = tid & 63;
    const int n    = blockIdx.x;          // one pred row per block

    // Load this row's 20 pred points (40 floats) into registers.
    float pr[40];
    const float4* pp = (const float4*)(pred + n * 40);
#pragma unroll
    for (int q = 0; q < 10; ++q) {
        float4 v = pp[q];
        pr[4*q+0] = v.x; pr[4*q+1] = v.y; pr[4*q+2] = v.z; pr[4*q+3] = v.w;
    }

    // Each wave scans a contiguous slice of gt rows.
    float bd = 3.4e38f;
    int   bi = 0x7fffffff;
    const int m_base = wave * M_PER_WAVE;
#pragma unroll
    for (int k = 0; k < K_ITERS; ++k) {
        const int m = m_base + k * 64 + lane;
        const float4* gp = (const float4*)(gt + m * 40);
        float acc = 0.0f;
        // NOTE: keep strict sequential point order 0..19 — round-2 absmax
        // was bitwise 0.0 vs the jnp reference; reordering risks argmin flips.
#pragma unroll
        for (int q = 0; q < 10; ++q) {
            float4 g = gp[q];
            float dx0 = pr[4*q+0] - g.x;
            float dy0 = pr[4*q+1] - g.y;
            float dx1 = pr[4*q+2] - g.z;
            float dy1 = pr[4*q+3] - g.w;
            acc += sqrtf(dx0*dx0 + dy0*dy0);
            acc += sqrtf(dx1*dx1 + dy1*dy1);
        }
        float dist = acc * (1.0f / P);
        if (dist < bd) { bd = dist; bi = m; }   // increasing m per lane -> first occurrence
    }

    // Wave-wide butterfly min+argmin; tie-break = smaller index.
#pragma unroll
    for (int off = 32; off; off >>= 1) {
        float od = __shfl_xor(bd, off, 64);
        int   oi = __shfl_xor(bi, off, 64);
        if (od < bd || (od == bd && oi < bi)) { bd = od; bi = oi; }
    }

    __shared__ float s_bd[WAVES];
    __shared__ int   s_bi[WAVES];
    __shared__ int   s_final;
    if (lane == 0) { s_bd[wave] = bd; s_bi[wave] = bi; }
    __syncthreads();

    if (tid == 0) {
        float fd = s_bd[0];
        int   fi = s_bi[0];
#pragma unroll
        for (int w = 1; w < WAVES; ++w) {
            float od = s_bd[w];
            int   oi = s_bi[w];
            if (od < fd || (od == fd && oi < fi)) { fd = od; fi = oi; }
        }
        s_final = fi;
        float conf = (fd > 2.0f) ? 0.0f : expf(-fd);
        out[40960 + n] = conf;
        out[41984 + n] = (float)fi;
    }
    __syncthreads();

    // Copy matched gt row (40 floats) — first 40 threads.
    if (tid < 40) {
        out[n * 40 + tid] = gt[s_final * 40 + tid];
    }
}

extern "C" void kernel_launch(void* const* d_in, const int* in_sizes, int n_in,
                              void* d_out, int out_size, void* d_ws, size_t ws_size,
                              hipStream_t stream) {
    const float* pred = (const float*)d_in[0];   // (1024, 20, 2) fp32
    const float* gt   = (const float*)d_in[1];   // (2048, 20, 2) fp32
    float* out = (float*)d_out;                  // 43008 floats
    (void)in_sizes; (void)n_in; (void)out_size; (void)d_ws; (void)ws_size;
    pm_kernel<<<N, THREADS, 0, stream>>>(pred, gt, out);
}

// Round 4
// 99.672 us; speedup vs baseline: 1.0603x; 1.0603x over previous
//
#include <hip/hip_runtime.h>

#define N 1024
#define M 2048
#define P 20
#define THREADS 256
#define WAVES 4
#define CHUNKS 64                 // gt chunks; 32 rows each
#define GROUPS 16                 // pred groups of 64 rows
#define ROWS_PER_CHUNK (M / CHUNKS)          // 32
#define ROWS_PER_WAVE (ROWS_PER_CHUNK / WAVES) // 8

// out layout (float*): matched_points [0,40960) row n at n*40
//                      confidence     [40960,41984) at 40960+n
//                      indices(float) [41984,43008) at 41984+n
// ws layout: float ws_d[CHUNKS][N] ; int ws_i[CHUNKS][N]  (512 KB total)

__global__ __launch_bounds__(THREADS) void pm_partial(
    const float* __restrict__ pred, const float* __restrict__ gt,
    float* __restrict__ ws_d, int* __restrict__ ws_i)
{
    const int tid   = threadIdx.x;
    const int wave  = tid >> 6;
    const int lane  = tid & 63;
    const int chunk = blockIdx.x;   // 0..63  -> gt rows [chunk*32, chunk*32+32)
    const int group = blockIdx.y;   // 0..15  -> pred rows [group*64, group*64+64)

    // Stage this group's 64 pred rows into LDS, fully coalesced.
    __shared__ float s_pred[64 * 40];
    const float4* psrc = (const float4*)(pred + group * 64 * 40);
    for (int t = tid; t < 64 * 40 / 4; t += THREADS)
        ((float4*)s_pred)[t] = psrc[t];
    __syncthreads();

    // lane <-> pred row: pull own row into registers (one-time LDS reads).
    float pr[40];
#pragma unroll
    for (int j = 0; j < 10; ++j) {
        float4 v = ((const float4*)(s_pred + lane * 40))[j];
        pr[4*j+0] = v.x; pr[4*j+1] = v.y; pr[4*j+2] = v.z; pr[4*j+3] = v.w;
    }

    // Scan this wave's gt rows at a WAVE-UNIFORM address (1 line/req, not 64).
    float bd = 3.4e38f;
    int   bi = 0x7fffffff;
    const int m0 = chunk * ROWS_PER_CHUNK + wave * ROWS_PER_WAVE;
    for (int r = 0; r < ROWS_PER_WAVE; ++r) {
        const int m_u = __builtin_amdgcn_readfirstlane(m0 + r);
        const float4* gp = (const float4*)(gt + m_u * 40);
        float acc = 0.0f;
        // EXACT same expression structure as round 2 (absmax was bitwise 0.0):
#pragma unroll
        for (int q = 0; q < 10; ++q) {
            float4 g = gp[q];
            float dx0 = pr[4*q+0] - g.x;
            float dy0 = pr[4*q+1] - g.y;
            float dx1 = pr[4*q+2] - g.z;
            float dy1 = pr[4*q+3] - g.w;
            acc += sqrtf(dx0*dx0 + dy0*dy0);
            acc += sqrtf(dx1*dx1 + dy1*dy1);
        }
        float dist = acc * (1.0f / P);
        if (dist < bd) { bd = dist; bi = m_u; }  // ascending m -> first occurrence
    }

    // Combine the block's 4 waves (ascending wave == ascending gt index).
    __shared__ float s_d[WAVES][64];
    __shared__ int   s_i[WAVES][64];
    s_d[wave][lane] = bd;
    s_i[wave][lane] = bi;
    __syncthreads();
    if (wave == 0) {
#pragma unroll
        for (int w = 1; w < WAVES; ++w) {
            float od = s_d[w][lane];
            int   oi = s_i[w][lane];
            if (od < bd) { bd = od; bi = oi; }   // strict <: earlier gt index wins ties
        }
        const int n = group * 64 + lane;
        ws_d[chunk * N + n] = bd;   // [chunk][row] layout: coalesced write & read
        ws_i[chunk * N + n] = bi;
    }
}

__global__ __launch_bounds__(THREADS) void pm_final(
    const float* __restrict__ gt, const float* __restrict__ ws_d,
    const int* __restrict__ ws_i, float* __restrict__ out)
{
    const int tid = threadIdx.x;
    const int n   = blockIdx.x * THREADS + tid;   // one pred row per thread

    float fd = ws_d[n];
    int   fi = ws_i[n];
    for (int c = 1; c < CHUNKS; ++c) {            // ascending chunk = ascending gt idx
        float od = ws_d[c * N + n];
        int   oi = ws_i[c * N + n];
        if (od < fd) { fd = od; fi = oi; }        // strict <: first occurrence
    }

    float conf = (fd > 2.0f) ? 0.0f : expf(-fd);
    out[40960 + n] = conf;
    out[41984 + n] = (float)fi;

    __shared__ int s_fi[THREADS];
    s_fi[tid] = fi;
    __syncthreads();

    // Cooperative matched-row copy: 256 rows * 40 floats, coalesced.
    const int base_row = blockIdx.x * THREADS;
    for (int t = tid; t < THREADS * 40; t += THREADS) {
        const int r = t / 40;
        const int e = t - r * 40;
        out[(base_row + r) * 40 + e] = gt[s_fi[r] * 40 + e];
    }
}

extern "C" void kernel_launch(void* const* d_in, const int* in_sizes, int n_in,
                              void* d_out, int out_size, void* d_ws, size_t ws_size,
                              hipStream_t stream) {
    const float* pred = (const float*)d_in[0];   // (1024, 20, 2) fp32
    const float* gt   = (const float*)d_in[1];   // (2048, 20, 2) fp32
    float* out  = (float*)d_out;                 // 43008 floats
    float* ws_d = (float*)d_ws;                  // CHUNKS*N floats
    int*   ws_i = (int*)((float*)d_ws + CHUNKS * N);
    (void)in_sizes; (void)n_in; (void)out_size; (void)ws_size;

    dim3 grid1(CHUNKS, GROUPS);
    pm_partial<<<grid1, THREADS, 0, stream>>>(pred, gt, ws_d, ws_i);
    pm_final<<<N / THREADS, THREADS, 0, stream>>>(gt, ws_d, ws_i, out);
}

// Round 5
// 87.231 us; speedup vs baseline: 1.2115x; 1.1426x over previous
//
#include <hip/hip_runtime.h>

#define N 1024
#define M 2048
#define P 20
#define THREADS 256
#define WAVES 4
#define CHUNKS 64                 // gt chunks; 32 rows each
#define GROUPS 16                 // pred groups of 64 rows
#define ROWS_PER_CHUNK (M / CHUNKS)          // 32
#define ROWS_PER_WAVE (ROWS_PER_CHUNK / WAVES) // 8

// out layout (float*): matched_points [0,40960) row n at n*40
//                      confidence     [40960,41984) at 40960+n
//                      indices(float) [41984,43008) at 41984+n
// ws layout: float ws_d[CHUNKS][N] ; int ws_i[CHUNKS][N]  (512 KB of the 256 MB ws)

__global__ __launch_bounds__(THREADS) void pm_partial(
    const float* __restrict__ pred, const float* __restrict__ gt,
    float* __restrict__ ws_d, int* __restrict__ ws_i)
{
    const int tid   = threadIdx.x;
    const int wave  = tid >> 6;
    const int lane  = tid & 63;
    const int chunk = blockIdx.x;   // 0..63  -> gt rows [chunk*32, chunk*32+32)
    const int group = blockIdx.y;   // 0..15  -> pred rows [group*64, group*64+64)

    // Stage this group's 64 pred rows into LDS, fully coalesced.
    __shared__ float s_pred[64 * 40];
    const float4* psrc = (const float4*)(pred + group * 64 * 40);
    for (int t = tid; t < 64 * 40 / 4; t += THREADS)
        ((float4*)s_pred)[t] = psrc[t];
    __syncthreads();

    // lane <-> pred row: pull own row into registers (one-time LDS reads).
    float pr[40];
#pragma unroll
    for (int j = 0; j < 10; ++j) {
        float4 v = ((const float4*)(s_pred + lane * 40))[j];
        pr[4*j+0] = v.x; pr[4*j+1] = v.y; pr[4*j+2] = v.z; pr[4*j+3] = v.w;
    }

    // Scan this wave's gt rows at a WAVE-UNIFORM address (scalar loads, 1 line/req).
    float bd = 3.4e38f;
    int   bi = 0x7fffffff;
    const int m0 = chunk * ROWS_PER_CHUNK + wave * ROWS_PER_WAVE;
    for (int r = 0; r < ROWS_PER_WAVE; ++r) {
        const int m_u = __builtin_amdgcn_readfirstlane(m0 + r);
        const float4* gp = (const float4*)(gt + m_u * 40);
        float acc = 0.0f;
        // Same summation ORDER as the bitwise-exact round-2 kernel; sqrt is the
        // raw v_sqrt_f32 (~1ulp) instead of the ~10-instr IEEE libm sequence.
#pragma unroll
        for (int q = 0; q < 10; ++q) {
            float4 g = gp[q];
            float dx0 = pr[4*q+0] - g.x;
            float dy0 = pr[4*q+1] - g.y;
            float dx1 = pr[4*q+2] - g.z;
            float dy1 = pr[4*q+3] - g.w;
            acc += __builtin_amdgcn_sqrtf(dx0*dx0 + dy0*dy0);
            acc += __builtin_amdgcn_sqrtf(dx1*dx1 + dy1*dy1);
        }
        float dist = acc * (1.0f / P);
        if (dist < bd) { bd = dist; bi = m_u; }  // ascending m -> first occurrence
    }

    // Combine the block's 4 waves (ascending wave == ascending gt index).
    __shared__ float s_d[WAVES][64];
    __shared__ int   s_i[WAVES][64];
    s_d[wave][lane] = bd;
    s_i[wave][lane] = bi;
    __syncthreads();
    if (wave == 0) {
#pragma unroll
        for (int w = 1; w < WAVES; ++w) {
            float od = s_d[w][lane];
            int   oi = s_i[w][lane];
            if (od < bd) { bd = od; bi = oi; }   // strict <: earlier gt index wins ties
        }
        const int n = group * 64 + lane;
        ws_d[chunk * N + n] = bd;   // [chunk][row] layout: coalesced write & read
        ws_i[chunk * N + n] = bi;
    }
}

__global__ __launch_bounds__(THREADS) void pm_final(
    const float* __restrict__ gt, const float* __restrict__ ws_d,
    const int* __restrict__ ws_i, float* __restrict__ out)
{
    const int tid = threadIdx.x;
    const int n   = blockIdx.x * THREADS + tid;   // one pred row per thread

    float fd = ws_d[n];
    int   fi = ws_i[n];
    for (int c = 1; c < CHUNKS; ++c) {            // ascending chunk = ascending gt idx
        float od = ws_d[c * N + n];
        int   oi = ws_i[c * N + n];
        if (od < fd) { fd = od; fi = oi; }        // strict <: first occurrence
    }

    float conf = (fd > 2.0f) ? 0.0f : expf(-fd);
    out[40960 + n] = conf;
    out[41984 + n] = (float)fi;

    __shared__ int s_fi[THREADS];
    s_fi[tid] = fi;
    __syncthreads();

    // Cooperative matched-row copy: 256 rows * 40 floats, coalesced.
    const int base_row = blockIdx.x * THREADS;
    for (int t = tid; t < THREADS * 40; t += THREADS) {
        const int r = t / 40;
        const int e = t - r * 40;
        out[(base_row + r) * 40 + e] = gt[s_fi[r] * 40 + e];
    }
}

extern "C" void kernel_launch(void* const* d_in, const int* in_sizes, int n_in,
                              void* d_out, int out_size, void* d_ws, size_t ws_size,
                              hipStream_t stream) {
    const float* pred = (const float*)d_in[0];   // (1024, 20, 2) fp32
    const float* gt   = (const float*)d_in[1];   // (2048, 20, 2) fp32
    float* out  = (float*)d_out;                 // 43008 floats
    float* ws_d = (float*)d_ws;                  // CHUNKS*N floats
    int*   ws_i = (int*)((float*)d_ws + CHUNKS * N);
    (void)in_sizes; (void)n_in; (void)out_size; (void)ws_size;

    dim3 grid1(CHUNKS, GROUPS);
    pm_partial<<<grid1, THREADS, 0, stream>>>(pred, gt, ws_d, ws_i);
    pm_final<<<N / THREADS, THREADS, 0, stream>>>(gt, ws_d, ws_i, out);
}